// Round 2
// baseline (763.665 us; speedup 1.0000x reference)
//
#include <hip/hip_runtime.h>
#include <cstdint>

#define NEG_INF (-__builtin_inff())

static constexpr int H = 2048;
static constexpr int W = 2048;
static constexpr int NIMG = 8;
static constexpr int ROWCHUNK = 256;

struct F4 { float x, y, z, w; };

__device__ __forceinline__ float fmax3(float a, float b, float c) {
    return fmaxf(fmaxf(a, b), c);
}

// 7-window maxes for 4 consecutive outputs from 10 inputs a0..a9
__device__ __forceinline__ void hmax7_4(float a0, float a1, float a2,
                                        float a3, float a4, float a5, float a6,
                                        float a7, float a8, float a9,
                                        float& m0, float& m1, float& m2, float& m3) {
    float p23 = fmaxf(a2, a3), p45 = fmaxf(a4, a5), p67 = fmaxf(a6, a7);
    float q25 = fmaxf(p23, p45), q47 = fmaxf(p45, p67);
    m0 = fmax3(fmaxf(a0, a1), q25, a6);
    m1 = fmax3(fmaxf(a1, a2), fmax3(a3, a4, a5), fmaxf(a6, a7));
    m2 = fmax3(p23, q47, a8);
    m3 = fmax3(fmaxf(a3, a4), fmax3(a5, a6, a7), fmaxf(a8, a9));
}

// compute horizontal 7-max (with zero-pad participation) for this thread's 4 cols
__device__ __forceinline__ void dilh4(const float* __restrict__ row, int c4, F4 cur,
                                      int lane, float& m0, float& m1, float& m2, float& m3) {
    float up_y = __shfl_up(cur.y, 1), up_z = __shfl_up(cur.z, 1), up_w = __shfl_up(cur.w, 1);
    float dn_x = __shfl_down(cur.x, 1), dn_y = __shfl_down(cur.y, 1), dn_z = __shfl_down(cur.z, 1);
    float l1, l2, l3, r0, r1, r2;
    if (lane == 0) {
        l1 = (c4 >= 3) ? row[c4 - 3] : NEG_INF;
        l2 = (c4 >= 2) ? row[c4 - 2] : NEG_INF;
        l3 = (c4 >= 1) ? row[c4 - 1] : NEG_INF;
    } else { l1 = up_y; l2 = up_z; l3 = up_w; }
    if (lane == 63) {
        r0 = (c4 + 4 < W) ? row[c4 + 4] : NEG_INF;
        r1 = (c4 + 5 < W) ? row[c4 + 5] : NEG_INF;
        r2 = (c4 + 6 < W) ? row[c4 + 6] : NEG_INF;
    } else { r0 = dn_x; r1 = dn_y; r2 = dn_z; }
    hmax7_4(l1, l2, l3, cur.x, cur.y, cur.z, cur.w, r0, r1, r2, m0, m1, m2, m3);
    if (c4 < 3) {
        m0 = fmaxf(m0, 0.f);
        if (c4 + 1 < 3) m1 = fmaxf(m1, 0.f);
        if (c4 + 2 < 3) m2 = fmaxf(m2, 0.f);
    }
    if (c4 + 3 > W - 4) {
        m3 = fmaxf(m3, 0.f);
        if (c4 + 2 > W - 4) m2 = fmaxf(m2, 0.f);
        if (c4 + 1 > W - 4) m1 = fmaxf(m1, 0.f);
    }
}

// Pass 1: per-image sums of dil_h and dil_v, vectorized 4 cols/thread.
__global__ __launch_bounds__(256) void k_sums(const float* __restrict__ x,
                                              double* __restrict__ sums) {
    const int tid  = threadIdx.x;
    const int lane = tid & 63;
    const int wid  = tid >> 6;
    const int c4   = blockIdx.x * 1024 + wid * 256 + lane * 4;
    const int r0   = blockIdx.y * ROWCHUNK;
    const int r1   = r0 + ROWCHUNK;
    const int b    = blockIdx.z;
    const float* img = x + (size_t)b * H * W;

    F4 w0, w1, w2, w3, w4, w5, w6;
    w0 = w1 = w2 = w3 = w4 = w5 = w6 = {NEG_INF, NEG_INF, NEG_INF, NEG_INF};
    double sh = 0.0, sv = 0.0;

    for (int ir = r0 - 3; ir < r1 + 3; ++ir) {
        w0 = w1; w1 = w2; w2 = w3; w3 = w4; w4 = w5; w5 = w6;
        F4 cur = {NEG_INF, NEG_INF, NEG_INF, NEG_INF};
        if (ir >= 0 && ir < H) {
            const float* row = img + (size_t)ir * W;
            float4 v = *reinterpret_cast<const float4*>(row + c4);
            cur = {v.x, v.y, v.z, v.w};
            if (ir >= r0 && ir < r1) {
                float m0, m1, m2, m3;
                dilh4(row, c4, cur, lane, m0, m1, m2, m3);
                sh += (double)((m0 + m1) + (m2 + m3));
            }
        }
        w6 = cur;
        const int j = ir - 3;
        if (j >= r0 && j < r1) {
            float mx = fmax3(fmax3(w0.x, w1.x, w2.x), fmax3(w3.x, w4.x, w5.x), w6.x);
            float my = fmax3(fmax3(w0.y, w1.y, w2.y), fmax3(w3.y, w4.y, w5.y), w6.y);
            float mz = fmax3(fmax3(w0.z, w1.z, w2.z), fmax3(w3.z, w4.z, w5.z), w6.z);
            float mw = fmax3(fmax3(w0.w, w1.w, w2.w), fmax3(w3.w, w4.w, w5.w), w6.w);
            if (j < 3 || j > H - 4) {
                mx = fmaxf(mx, 0.f); my = fmaxf(my, 0.f);
                mz = fmaxf(mz, 0.f); mw = fmaxf(mw, 0.f);
            }
            sv += (double)((mx + my) + (mz + mw));
        }
    }

    for (int off = 32; off > 0; off >>= 1) {
        sh += __shfl_down(sh, off);
        sv += __shfl_down(sv, off);
    }
    __shared__ double sdh[4], sdv[4];
    if (lane == 0) { sdh[wid] = sh; sdv[wid] = sv; }
    __syncthreads();
    if (tid == 0) {
        atomicAdd(&sums[b],        sdh[0] + sdh[1] + sdh[2] + sdh[3]);
        atomicAdd(&sums[NIMG + b], sdv[0] + sdv[1] + sdv[2] + sdv[3]);
    }
}

// Pass 2a: orientation 1 count, vectorized 4 cols/thread.
__global__ __launch_bounds__(256) void k_count1(const float* __restrict__ x,
                                                const double* __restrict__ sums,
                                                unsigned int* __restrict__ cnts) {
    const int tid  = threadIdx.x;
    const int lane = tid & 63;
    const int wid  = tid >> 6;
    const int c4   = blockIdx.x * 1024 + wid * 256 + lane * 4;
    const int r0   = blockIdx.y * ROWCHUNK;
    const int r1   = r0 + ROWCHUNK;
    const int b    = blockIdx.z;
    const float* img = x + (size_t)b * H * W;
    const float thr = (float)(sums[b] * (1.0 / ((double)H * (double)W)));

    int bi_m1 = 0, bi_m2 = 0, er_m1 = 0, er_m2 = 0;
    unsigned int cnt = 0;

    for (int r = r0 - 2; r < r1 + 2; ++r) {
        int bi = 0;
        if (r >= 0 && r < H) {
            const float* row = img + (size_t)r * W;
            float4 v = *reinterpret_cast<const float4*>(row + c4);
            F4 cur = {v.x, v.y, v.z, v.w};
            float m0, m1, m2, m3;
            dilh4(row, c4, cur, lane, m0, m1, m2, m3);
            bi = ((cur.x > thr && cur.x == m0) ? 1 : 0)
               | ((cur.y > thr && cur.y == m1) ? 2 : 0)
               | ((cur.z > thr && cur.z == m2) ? 4 : 0)
               | ((cur.w > thr && cur.w == m3) ? 8 : 0);
        }
        int er = bi_m2 & bi_m1 & bi;
        const int i = r - 2;
        if (i >= r0 && i < r1) cnt += (unsigned int)__popc(er_m2 | er_m1 | er);
        er_m2 = er_m1; er_m1 = er;
        bi_m2 = bi_m1; bi_m1 = bi;
    }

    for (int off = 32; off > 0; off >>= 1) cnt += __shfl_down(cnt, off);
    __shared__ unsigned int sc[4];
    if (lane == 0) sc[wid] = cnt;
    __syncthreads();
    if (tid == 0) atomicAdd(&cnts[0], sc[0] + sc[1] + sc[2] + sc[3]);
}

// Pass 2b: orientation 2 count (proven ballot structure, scalar loads).
__global__ __launch_bounds__(256) void k_count2(const float* __restrict__ x,
                                                const double* __restrict__ sums,
                                                unsigned int* __restrict__ cnts) {
    const int tid  = threadIdx.x;
    const int lane = tid & 63;
    const int wid  = tid >> 6;
    const int w    = blockIdx.x * 4 + wid;
    const int base = w * 60 - 2;
    const int c    = base + lane;
    const bool inimg = (c >= 0 && c < W);
    const int r0 = blockIdx.y * ROWCHUNK;
    const int r1 = r0 + ROWCHUNK;
    const int b  = blockIdx.z;
    const float* img = x + (size_t)b * H * W;
    const float thr = (float)(sums[NIMG + b] * (1.0 / ((double)H * (double)W)));

    const unsigned long long vmask = __ballot(lane >= 2 && lane <= 61 && inimg);

    float v0, v1, v2, v3, v4, v5, v6;
    v0 = v1 = v2 = v3 = v4 = v5 = v6 = NEG_INF;
    unsigned int cnt = 0;

    for (int ir = r0 - 3; ir < r1 + 3; ++ir) {
        v0 = v1; v1 = v2; v2 = v3; v3 = v4; v4 = v5; v5 = v6;
        float center = NEG_INF;
        if (ir >= 0 && ir < H && inimg) center = img[(size_t)ir * W + c];
        v6 = center;
        const int j = ir - 3;
        if (j >= r0 && j < r1) {
            float m = fmax3(fmax3(v0, v1, v2), fmax3(v3, v4, v5), v6);
            if (j < 3 || j > H - 4) m = fmaxf(m, 0.0f);
            float xc = v3;
            int bi = inimg && (xc > thr) && (xc == m);
            unsigned long long bm = __ballot(bi);
            unsigned long long er = (bm << 1) & bm & (bm >> 1);
            unsigned long long op = (er << 1) | er | (er >> 1);
            cnt += __popcll(op & vmask);
        }
    }

    __shared__ unsigned int sc[4];
    if (lane == 0) sc[wid] = cnt;
    __syncthreads();
    if (tid == 0) atomicAdd(&cnts[1], sc[0] + sc[1] + sc[2] + sc[3]);
}

__global__ void k_final(const unsigned int* __restrict__ cnts,
                        int* __restrict__ out) {
    out[0] = (cnts[0] < cnts[1]) ? 1 : 0;
}

extern "C" void kernel_launch(void* const* d_in, const int* in_sizes, int n_in,
                              void* d_out, int out_size, void* d_ws, size_t ws_size,
                              hipStream_t stream) {
    const float* x = (const float*)d_in[0];
    int* out = (int*)d_out;
    double* sums = (double*)d_ws;
    unsigned int* cnts = (unsigned int*)((char*)d_ws + 128);

    hipMemsetAsync(d_ws, 0, 256, stream);

    dim3 blk(256);
    k_sums  <<<dim3(2, 8, 8), blk, 0, stream>>>(x, sums);
    k_count1<<<dim3(2, 8, 8), blk, 0, stream>>>(x, sums, cnts);
    k_count2<<<dim3(9, 8, 8), blk, 0, stream>>>(x, sums, cnts);
    k_final <<<1, 1, 0, stream>>>(cnts, out);
}

// Round 3
// 369.197 us; speedup vs baseline: 2.0684x; 2.0684x over previous
//
#include <hip/hip_runtime.h>
#include <cstdint>

#define NEG_INF (-__builtin_inff())

static constexpr int H = 2048;
static constexpr int W = 2048;
static constexpr int NIMG = 8;

struct F4 { float x, y, z, w; };

__device__ __forceinline__ float fmax3(float a, float b, float c) {
    return fmaxf(fmaxf(a, b), c);
}

// 7-window maxes for 4 consecutive outputs from 10 inputs a0..a9
__device__ __forceinline__ void hmax7_4(float a0, float a1, float a2,
                                        float a3, float a4, float a5, float a6,
                                        float a7, float a8, float a9,
                                        float& m0, float& m1, float& m2, float& m3) {
    float p23 = fmaxf(a2, a3), p45 = fmaxf(a4, a5), p67 = fmaxf(a6, a7);
    float q25 = fmaxf(p23, p45), q47 = fmaxf(p45, p67);
    m0 = fmax3(fmaxf(a0, a1), q25, a6);
    m1 = fmax3(fmaxf(a1, a2), fmax3(a3, a4, a5), fmaxf(a6, a7));
    m2 = fmax3(p23, q47, a8);
    m3 = fmax3(fmaxf(a3, a4), fmax3(a5, a6, a7), fmaxf(a8, a9));
}

// horizontal 7-max (with zero-pad participation) for this thread's 4 cols
__device__ __forceinline__ void dilh4(const float* __restrict__ row, int c4, F4 cur,
                                      int lane, float& m0, float& m1, float& m2, float& m3) {
    float up_y = __shfl_up(cur.y, 1), up_z = __shfl_up(cur.z, 1), up_w = __shfl_up(cur.w, 1);
    float dn_x = __shfl_down(cur.x, 1), dn_y = __shfl_down(cur.y, 1), dn_z = __shfl_down(cur.z, 1);
    float l1, l2, l3, r0, r1, r2;
    if (lane == 0) {
        l1 = (c4 >= 3) ? row[c4 - 3] : NEG_INF;
        l2 = (c4 >= 2) ? row[c4 - 2] : NEG_INF;
        l3 = (c4 >= 1) ? row[c4 - 1] : NEG_INF;
    } else { l1 = up_y; l2 = up_z; l3 = up_w; }
    if (lane == 63) {
        r0 = (c4 + 4 < W) ? row[c4 + 4] : NEG_INF;
        r1 = (c4 + 5 < W) ? row[c4 + 5] : NEG_INF;
        r2 = (c4 + 6 < W) ? row[c4 + 6] : NEG_INF;
    } else { r0 = dn_x; r1 = dn_y; r2 = dn_z; }
    hmax7_4(l1, l2, l3, cur.x, cur.y, cur.z, cur.w, r0, r1, r2, m0, m1, m2, m3);
    if (c4 < 3) {
        m0 = fmaxf(m0, 0.f);
        if (c4 + 1 < 3) m1 = fmaxf(m1, 0.f);
        if (c4 + 2 < 3) m2 = fmaxf(m2, 0.f);
    }
    if (c4 + 3 > W - 4) {
        m3 = fmaxf(m3, 0.f);
        if (c4 + 2 > W - 4) m2 = fmaxf(m2, 0.f);
        if (c4 + 1 > W - 4) m1 = fmaxf(m1, 0.f);
    }
}

// Pass 1: per-image sums of dil_h and dil_v, 4 cols/thread.
// RC=16 -> grid (2,128,8) = 2048 blocks = 32 waves/CU for latency hiding.
template<int RC>
__global__ __launch_bounds__(256) void k_sums(const float* __restrict__ x,
                                              double* __restrict__ sums) {
    const int tid  = threadIdx.x;
    const int lane = tid & 63;
    const int wid  = tid >> 6;
    const int c4   = blockIdx.x * 1024 + wid * 256 + lane * 4;
    const int r0   = blockIdx.y * RC;
    const int r1   = r0 + RC;
    const int b    = blockIdx.z;
    const float* img = x + (size_t)b * H * W;

    F4 w0, w1, w2, w3, w4, w5, w6;
    w0 = w1 = w2 = w3 = w4 = w5 = w6 = {NEG_INF, NEG_INF, NEG_INF, NEG_INF};
    double sh = 0.0, sv = 0.0;

    for (int ir = r0 - 3; ir < r1 + 3; ++ir) {
        w0 = w1; w1 = w2; w2 = w3; w3 = w4; w4 = w5; w5 = w6;
        F4 cur = {NEG_INF, NEG_INF, NEG_INF, NEG_INF};
        if (ir >= 0 && ir < H) {
            const float* row = img + (size_t)ir * W;
            float4 v = *reinterpret_cast<const float4*>(row + c4);
            cur = {v.x, v.y, v.z, v.w};
            if (ir >= r0 && ir < r1) {
                float m0, m1, m2, m3;
                dilh4(row, c4, cur, lane, m0, m1, m2, m3);
                sh += (double)((m0 + m1) + (m2 + m3));
            }
        }
        w6 = cur;
        const int j = ir - 3;
        if (j >= r0 && j < r1) {
            float mx = fmax3(fmax3(w0.x, w1.x, w2.x), fmax3(w3.x, w4.x, w5.x), w6.x);
            float my = fmax3(fmax3(w0.y, w1.y, w2.y), fmax3(w3.y, w4.y, w5.y), w6.y);
            float mz = fmax3(fmax3(w0.z, w1.z, w2.z), fmax3(w3.z, w4.z, w5.z), w6.z);
            float mw = fmax3(fmax3(w0.w, w1.w, w2.w), fmax3(w3.w, w4.w, w5.w), w6.w);
            if (j < 3 || j > H - 4) {
                mx = fmaxf(mx, 0.f); my = fmaxf(my, 0.f);
                mz = fmaxf(mz, 0.f); mw = fmaxf(mw, 0.f);
            }
            sv += (double)((mx + my) + (mz + mw));
        }
    }

    for (int off = 32; off > 0; off >>= 1) {
        sh += __shfl_down(sh, off);
        sv += __shfl_down(sv, off);
    }
    __shared__ double sdh[4], sdv[4];
    if (lane == 0) { sdh[wid] = sh; sdv[wid] = sv; }
    __syncthreads();
    if (tid == 0) {
        atomicAdd(&sums[b],        sdh[0] + sdh[1] + sdh[2] + sdh[3]);
        atomicAdd(&sums[NIMG + b], sdv[0] + sdv[1] + sdv[2] + sdv[3]);
    }
}

// Pass 2 merged: blockIdx.x < C1X -> orientation-1 count (4 cols/thread pipeline);
// else -> orientation-2 count (ballot, 60-col stripes). One dispatch = both run
// concurrently on the L3-resident input.
template<int RC, int C1X>
__global__ __launch_bounds__(256) void k_counts(const float* __restrict__ x,
                                                const double* __restrict__ sums,
                                                unsigned int* __restrict__ cnts) {
    const int tid  = threadIdx.x;
    const int lane = tid & 63;
    const int wid  = tid >> 6;
    const int r0   = blockIdx.y * RC;
    const int r1   = r0 + RC;
    const int b    = blockIdx.z;
    const float* img = x + (size_t)b * H * W;
    __shared__ unsigned int sc[4];

    if (blockIdx.x < C1X) {
        // ---- orientation 1: bi=(x>thr1)&(x==dil_h); vertical 3-open ----
        const int c4  = blockIdx.x * 1024 + wid * 256 + lane * 4;
        const float thr = (float)(sums[b] * (1.0 / ((double)H * (double)W)));

        int bi_m1 = 0, bi_m2 = 0, er_m1 = 0, er_m2 = 0;
        unsigned int cnt = 0;

        for (int r = r0 - 2; r < r1 + 2; ++r) {
            int bi = 0;
            if (r >= 0 && r < H) {
                const float* row = img + (size_t)r * W;
                float4 v = *reinterpret_cast<const float4*>(row + c4);
                F4 cur = {v.x, v.y, v.z, v.w};
                float m0, m1, m2, m3;
                dilh4(row, c4, cur, lane, m0, m1, m2, m3);
                bi = ((cur.x > thr && cur.x == m0) ? 1 : 0)
                   | ((cur.y > thr && cur.y == m1) ? 2 : 0)
                   | ((cur.z > thr && cur.z == m2) ? 4 : 0)
                   | ((cur.w > thr && cur.w == m3) ? 8 : 0);
            }
            int er = bi_m2 & bi_m1 & bi;
            const int i = r - 2;
            if (i >= r0 && i < r1) cnt += (unsigned int)__popc(er_m2 | er_m1 | er);
            er_m2 = er_m1; er_m1 = er;
            bi_m2 = bi_m1; bi_m1 = bi;
        }

        for (int off = 32; off > 0; off >>= 1) cnt += __shfl_down(cnt, off);
        if (lane == 0) sc[wid] = cnt;
        __syncthreads();
        if (tid == 0) atomicAdd(&cnts[0], sc[0] + sc[1] + sc[2] + sc[3]);
    } else {
        // ---- orientation 2: bi=(x>thr2)&(x==dil_v); horizontal 3-open ----
        const int w    = (blockIdx.x - C1X) * 4 + wid;
        const int base = w * 60 - 2;
        const int c    = base + lane;
        const bool inimg = (c >= 0 && c < W);
        const float thr = (float)(sums[NIMG + b] * (1.0 / ((double)H * (double)W)));

        const unsigned long long vmask = __ballot(lane >= 2 && lane <= 61 && inimg);

        float v0, v1, v2, v3, v4, v5, v6;
        v0 = v1 = v2 = v3 = v4 = v5 = v6 = NEG_INF;
        unsigned int cnt = 0;

        for (int ir = r0 - 3; ir < r1 + 3; ++ir) {
            v0 = v1; v1 = v2; v2 = v3; v3 = v4; v4 = v5; v5 = v6;
            float center = NEG_INF;
            if (ir >= 0 && ir < H && inimg) center = img[(size_t)ir * W + c];
            v6 = center;
            const int j = ir - 3;
            if (j >= r0 && j < r1) {
                float m = fmax3(fmax3(v0, v1, v2), fmax3(v3, v4, v5), v6);
                if (j < 3 || j > H - 4) m = fmaxf(m, 0.0f);
                float xc = v3;
                int bi = inimg && (xc > thr) && (xc == m);
                unsigned long long bm = __ballot(bi);
                unsigned long long er = (bm << 1) & bm & (bm >> 1);
                unsigned long long op = (er << 1) | er | (er >> 1);
                cnt += __popcll(op & vmask);
            }
        }

        if (lane == 0) sc[wid] = cnt;  // cnt wave-uniform
        __syncthreads();
        if (tid == 0) atomicAdd(&cnts[1], sc[0] + sc[1] + sc[2] + sc[3]);
    }
}

__global__ void k_final(const unsigned int* __restrict__ cnts,
                        int* __restrict__ out) {
    out[0] = (cnts[0] < cnts[1]) ? 1 : 0;
}

extern "C" void kernel_launch(void* const* d_in, const int* in_sizes, int n_in,
                              void* d_out, int out_size, void* d_ws, size_t ws_size,
                              hipStream_t stream) {
    const float* x = (const float*)d_in[0];
    int* out = (int*)d_out;
    double* sums = (double*)d_ws;
    unsigned int* cnts = (unsigned int*)((char*)d_ws + 128);

    hipMemsetAsync(d_ws, 0, 256, stream);

    dim3 blk(256);
    // RC=16: k_sums 2048 blocks (32 waves/CU); k_counts 11264 blocks.
    k_sums<16>      <<<dim3(2, 128, 8), blk, 0, stream>>>(x, sums);
    k_counts<16, 2> <<<dim3(11, 128, 8), blk, 0, stream>>>(x, sums, cnts);
    k_final         <<<1, 1, 0, stream>>>(cnts, out);
}

// Round 4
// 273.430 us; speedup vs baseline: 2.7929x; 1.3502x over previous
//
#include <hip/hip_runtime.h>
#include <cstdint>

#define NEG_INF (-__builtin_inff())

static constexpr int H = 2048;
static constexpr int W = 2048;
static constexpr int NIMG = 8;
static constexpr int STR = 248;   // counted cols per wave-stripe in k_counts

struct F4 { float x, y, z, w; };

__device__ __forceinline__ F4 ld4(const float* __restrict__ p) {
    float4 v = *reinterpret_cast<const float4*>(p);
    return {v.x, v.y, v.z, v.w};
}

__device__ __forceinline__ float fmax3(float a, float b, float c) {
    return fmaxf(fmaxf(a, b), c);
}

// 7-window maxes for 4 consecutive outputs from 10 inputs a0..a9 (verified)
__device__ __forceinline__ void hmax7_4(float a0, float a1, float a2,
                                        float a3, float a4, float a5, float a6,
                                        float a7, float a8, float a9,
                                        float& m0, float& m1, float& m2, float& m3) {
    float p23 = fmaxf(a2, a3), p45 = fmaxf(a4, a5), p67 = fmaxf(a6, a7);
    float q25 = fmaxf(p23, p45), q47 = fmaxf(p45, p67);
    m0 = fmax3(fmaxf(a0, a1), q25, a6);
    m1 = fmax3(fmaxf(a1, a2), fmax3(a3, a4, a5), fmaxf(a6, a7));
    m2 = fmax3(p23, q47, a8);
    m3 = fmax3(fmaxf(a3, a4), fmax3(a5, a6, a7), fmaxf(a8, a9));
}

// Pass 1: per-image sums of dil_h and dil_v. 4 cols/thread, branchless clamped
// loads (pipelinable), compile-time trip count -> full unroll.
template<int RC>
__global__ __launch_bounds__(256) void k_sums(const float* __restrict__ x,
                                              double* __restrict__ sums) {
    const int tid = threadIdx.x;
    const int c4  = blockIdx.x * 1024 + tid * 4;
    const int r0  = blockIdx.y * RC;
    const int b   = blockIdx.z;
    const float* img = x + (size_t)b * H * W;

    const bool laV = (c4 >= 4);
    const bool raV = (c4 + 8 <= W);
    const int  lA  = laV ? (c4 - 4) : 0;
    const int  rA  = raV ? (c4 + 4) : (W - 4);
    // column zero-pad participation for dil_h (hoisted per thread)
    const float pad0 = (c4 + 0 < 3 || c4 + 0 > W - 4) ? 0.f : NEG_INF;
    const float pad1 = (c4 + 1 < 3 || c4 + 1 > W - 4) ? 0.f : NEG_INF;
    const float pad2 = (c4 + 2 < 3 || c4 + 2 > W - 4) ? 0.f : NEG_INF;
    const float pad3 = (c4 + 3 < 3 || c4 + 3 > W - 4) ? 0.f : NEG_INF;

    F4 w0, w1, w2, w3, w4, w5, w6;
    w0 = w1 = w2 = w3 = w4 = w5 = w6 = {NEG_INF, NEG_INF, NEG_INF, NEG_INF};
    double sh = 0.0, sv = 0.0;

#pragma unroll
    for (int t = 0; t < RC + 6; ++t) {
        const int ir  = r0 - 3 + t;
        w0 = w1; w1 = w2; w2 = w3; w3 = w4; w4 = w5; w5 = w6;
        const int irc = min(max(ir, 0), H - 1);
        const float* row = img + (size_t)irc * W;
        F4 cur = ld4(row + c4);                    // unconditional load
        const bool rv = (ir >= 0) && (ir < H);

        if (t >= 3 && t < RC + 3) {                // ir in [r0, r1): valid rows
            F4 la = ld4(row + lA);
            F4 ra = ld4(row + rA);
            if (!laV) la = {NEG_INF, NEG_INF, NEG_INF, NEG_INF};
            if (!raV) ra = {NEG_INF, NEG_INF, NEG_INF, NEG_INF};
            float m0, m1, m2, m3;
            hmax7_4(la.y, la.z, la.w, cur.x, cur.y, cur.z, cur.w,
                    ra.x, ra.y, ra.z, m0, m1, m2, m3);
            m0 = fmaxf(m0, pad0); m1 = fmaxf(m1, pad1);
            m2 = fmaxf(m2, pad2); m3 = fmaxf(m3, pad3);
            sh += (double)((m0 + m1) + (m2 + m3));
        }

        F4 cw = cur;
        if (!rv) cw = {NEG_INF, NEG_INF, NEG_INF, NEG_INF};
        w6 = cw;

        const int j = ir - 3;
        if (t >= 6) {                              // j in [r0, r1)
            const float rpad = (j < 3 || j > H - 4) ? 0.f : NEG_INF;
            float mx = fmax3(fmax3(w0.x, w1.x, w2.x), fmax3(w3.x, w4.x, w5.x), w6.x);
            float my = fmax3(fmax3(w0.y, w1.y, w2.y), fmax3(w3.y, w4.y, w5.y), w6.y);
            float mz = fmax3(fmax3(w0.z, w1.z, w2.z), fmax3(w3.z, w4.z, w5.z), w6.z);
            float mw = fmax3(fmax3(w0.w, w1.w, w2.w), fmax3(w3.w, w4.w, w5.w), w6.w);
            mx = fmaxf(mx, rpad); my = fmaxf(my, rpad);
            mz = fmaxf(mz, rpad); mw = fmaxf(mw, rpad);
            sv += (double)((mx + my) + (mz + mw));
        }
    }

    const int lane = tid & 63, wid = tid >> 6;
    for (int off = 32; off > 0; off >>= 1) {
        sh += __shfl_down(sh, off);
        sv += __shfl_down(sv, off);
    }
    __shared__ double sdh[4], sdv[4];
    if (lane == 0) { sdh[wid] = sh; sdv[wid] = sv; }
    __syncthreads();
    if (tid == 0) {
        const int bk = blockIdx.y & 1;
        atomicAdd(&sums[2 * b + bk],      sdh[0] + sdh[1] + sdh[2] + sdh[3]);
        atomicAdd(&sums[16 + 2 * b + bk], sdv[0] + sdv[1] + sdv[2] + sdv[3]);
    }
}

// Pass 2 fused: both orientation counts in ONE read of x.
// Per-wave 248-col stripe (+4-col halo each side), 4 cols/thread bitmasks.
template<int RC>
__global__ __launch_bounds__(256) void k_counts(const float* __restrict__ x,
                                                const double* __restrict__ sums,
                                                unsigned int* __restrict__ cnts) {
    const int tid  = threadIdx.x;
    const int lane = tid & 63;
    const int wid  = tid >> 6;
    const int w    = blockIdx.x * 4 + wid;
    if (w >= 9) return;                     // no barriers below -> safe
    const int cstart = w * STR;
    const int c4   = cstart - 4 + lane * 4;
    const int r0   = blockIdx.y * RC;
    const int b    = blockIdx.z;
    const float* img = x + (size_t)b * H * W;

    const double invHW = 1.0 / ((double)H * (double)W);
    const float thr1 = (float)((sums[2 * b] + sums[2 * b + 1]) * invHW);
    const float thr2 = (float)((sums[16 + 2 * b] + sums[16 + 2 * b + 1]) * invHW);

    int cmask = 0, imask = 0;
#pragma unroll
    for (int k = 0; k < 4; ++k) {
        const int col = c4 + k;
        if (col >= cstart && col < cstart + STR && col < W) cmask |= 1 << k;
        if (col >= 0 && col < W)                            imask |= 1 << k;
    }
    const bool curV = (c4 >= 0) && (c4 <= W - 4);
    const bool laV  = (c4 - 4 >= 0) && (c4 - 4 <= W - 4);
    const bool raV  = (c4 + 4 >= 0) && (c4 + 4 <= W - 4);
    const int cA = min(max(c4, 0), W - 4);
    const int lA = min(max(c4 - 4, 0), W - 4);
    const int rA = min(max(c4 + 4, 0), W - 4);
    const float pad0 = (c4 + 0 < 3 || c4 + 0 > W - 4) ? 0.f : NEG_INF;
    const float pad1 = (c4 + 1 < 3 || c4 + 1 > W - 4) ? 0.f : NEG_INF;
    const float pad2 = (c4 + 2 < 3 || c4 + 2 > W - 4) ? 0.f : NEG_INF;
    const float pad3 = (c4 + 3 < 3 || c4 + 3 > W - 4) ? 0.f : NEG_INF;

    F4 w0, w1, w2, w3, w4, w5, w6;
    w0 = w1 = w2 = w3 = w4 = w5 = w6 = {NEG_INF, NEG_INF, NEG_INF, NEG_INF};
    int bi_m1 = 0, bi_m2 = 0, er_m1 = 0, er_m2 = 0;
    unsigned int cnt1 = 0, cnt2 = 0;

#pragma unroll
    for (int t = 0; t < RC + 6; ++t) {
        const int ir = r0 - 3 + t;
        w0 = w1; w1 = w2; w2 = w3; w3 = w4; w4 = w5; w5 = w6;
        const int irc = min(max(ir, 0), H - 1);
        const float* row = img + (size_t)irc * W;
        F4 cur = ld4(row + cA);                    // unconditional
        if (!curV) cur = {NEG_INF, NEG_INF, NEG_INF, NEG_INF};
        const bool rv = (ir >= 0) && (ir < H);

        // ---- orientation 1: bi rows ir in [r0-2, r1+1] -> t in [1, RC+4] ----
        if (t >= 1 && t <= RC + 4) {
            F4 la = ld4(row + lA);
            F4 ra = ld4(row + rA);
            if (!laV) la = {NEG_INF, NEG_INF, NEG_INF, NEG_INF};
            if (!raV) ra = {NEG_INF, NEG_INF, NEG_INF, NEG_INF};
            float m0, m1, m2, m3;
            hmax7_4(la.y, la.z, la.w, cur.x, cur.y, cur.z, cur.w,
                    ra.x, ra.y, ra.z, m0, m1, m2, m3);
            m0 = fmaxf(m0, pad0); m1 = fmaxf(m1, pad1);
            m2 = fmaxf(m2, pad2); m3 = fmaxf(m3, pad3);
            int bi = ((cur.x > thr1 && cur.x == m0) ? 1 : 0)
                   | ((cur.y > thr1 && cur.y == m1) ? 2 : 0)
                   | ((cur.z > thr1 && cur.z == m2) ? 4 : 0)
                   | ((cur.w > thr1 && cur.w == m3) ? 8 : 0);
            if (!rv) bi = 0;
            const int er = bi_m2 & bi_m1 & bi;
            if (t >= 5) cnt1 += (unsigned int)__popc((er_m2 | er_m1 | er) & cmask);
            er_m2 = er_m1; er_m1 = er;
            bi_m2 = bi_m1; bi_m1 = bi;
        }

        F4 cw = cur;
        if (!rv) cw = {NEG_INF, NEG_INF, NEG_INF, NEG_INF};
        w6 = cw;

        // ---- orientation 2: dil_v row j = ir-3 in [r0, r1) -> t >= 6 ----
        if (t >= 6) {
            const int j = ir - 3;
            const float rpad = (j < 3 || j > H - 4) ? 0.f : NEG_INF;
            float mx = fmax3(fmax3(w0.x, w1.x, w2.x), fmax3(w3.x, w4.x, w5.x), w6.x);
            float my = fmax3(fmax3(w0.y, w1.y, w2.y), fmax3(w3.y, w4.y, w5.y), w6.y);
            float mz = fmax3(fmax3(w0.z, w1.z, w2.z), fmax3(w3.z, w4.z, w5.z), w6.z);
            float mw = fmax3(fmax3(w0.w, w1.w, w2.w), fmax3(w3.w, w4.w, w5.w), w6.w);
            mx = fmaxf(mx, rpad); my = fmaxf(my, rpad);
            mz = fmaxf(mz, rpad); mw = fmaxf(mw, rpad);
            int bi2 = ((w3.x > thr2 && w3.x == mx) ? 1 : 0)
                    | ((w3.y > thr2 && w3.y == my) ? 2 : 0)
                    | ((w3.z > thr2 && w3.z == mz) ? 4 : 0)
                    | ((w3.w > thr2 && w3.w == mw) ? 8 : 0);
            bi2 &= imask;
            const int pb = __shfl_up(bi2, 1);
            const int nb = __shfl_down(bi2, 1);
            // m6 bit k = bi at col c4-1+k
            const int m6  = (bi2 << 1) | ((pb >> 3) & 1) | ((nb & 1) << 5);
            const int er2 = (m6 & (m6 >> 1) & (m6 >> 2)) & 0xF;   // er at c4..c4+3
            const int per_ = ((pb >> 2) & (pb >> 3) & bi2) & 1;    // er at c4-1
            const int ner_ = ((bi2 >> 3) & nb & (nb >> 1)) & 1;    // er at c4+4
            const int e6 = (er2 << 1) | per_ | (ner_ << 5);        // er at c4-1+k
            const int t6 = e6 | (e6 >> 1) | (e6 >> 2);             // op at c4+k
            cnt2 += (unsigned int)__popc(t6 & cmask);
        }
    }

    for (int off = 32; off > 0; off >>= 1) {
        cnt1 += __shfl_down(cnt1, off);
        cnt2 += __shfl_down(cnt2, off);
    }
    if (lane == 0) {
        const int bkt = (blockIdx.y * 9 + w) & 63;
        atomicAdd(&cnts[bkt],      cnt1);
        atomicAdd(&cnts[64 + bkt], cnt2);
    }
}

__global__ void k_final(const unsigned int* __restrict__ cnts,
                        int* __restrict__ out) {
    const int l = threadIdx.x;
    unsigned int a = cnts[l], c = cnts[64 + l];
    for (int off = 32; off > 0; off >>= 1) {
        a += __shfl_down(a, off);
        c += __shfl_down(c, off);
    }
    if (l == 0) out[0] = (a < c) ? 1 : 0;
}

extern "C" void kernel_launch(void* const* d_in, const int* in_sizes, int n_in,
                              void* d_out, int out_size, void* d_ws, size_t ws_size,
                              hipStream_t stream) {
    const float* x = (const float*)d_in[0];
    int* out = (int*)d_out;
    double* sums = (double*)d_ws;                                  // 32 doubles
    unsigned int* cnts = (unsigned int*)((char*)d_ws + 256);       // 128 uints

    hipMemsetAsync(d_ws, 0, 1024, stream);

    dim3 blk(256);
    k_sums<16>   <<<dim3(2, 128, 8), blk, 0, stream>>>(x, sums);
    k_counts<16> <<<dim3(3, 128, 8), blk, 0, stream>>>(x, sums, cnts);
    k_final      <<<1, 64, 0, stream>>>(cnts, out);
}

// Round 5
// 247.091 us; speedup vs baseline: 3.0906x; 1.1066x over previous
//
#include <hip/hip_runtime.h>
#include <cstdint>

#define NEG_INF (-__builtin_inff())

static constexpr int H = 2048;
static constexpr int W = 2048;
static constexpr int STR = 248;     // counted cols per wave stripe (9 stripes)
static constexpr int RC  = 8;       // rows counted per wave
static constexpr int NR  = RC + 6;  // rows held in registers

struct F4 { float x, y, z, w; };

__device__ __forceinline__ F4 ld4(const float* __restrict__ p) {
    float4 v = *reinterpret_cast<const float4*>(p);
    return {v.x, v.y, v.z, v.w};
}

__device__ __forceinline__ float fmax3(float a, float b, float c) {
    return fmaxf(fmaxf(a, b), c);
}

// 7-window maxes for 4 consecutive outputs from 10 inputs a0..a9 (verified r1-r4)
__device__ __forceinline__ void hmax7_4(float a0, float a1, float a2,
                                        float a3, float a4, float a5, float a6,
                                        float a7, float a8, float a9,
                                        float& m0, float& m1, float& m2, float& m3) {
    float p23 = fmaxf(a2, a3), p45 = fmaxf(a4, a5), p67 = fmaxf(a6, a7);
    float q25 = fmaxf(p23, p45), q47 = fmaxf(p45, p67);
    m0 = fmax3(fmaxf(a0, a1), q25, a6);
    m1 = fmax3(fmaxf(a1, a2), fmax3(a3, a4, a5), fmaxf(a6, a7));
    m2 = fmax3(p23, q47, a8);
    m3 = fmax3(fmaxf(a3, a4), fmax3(a5, a6, a7), fmaxf(a8, a9));
}

// ---- shared per-thread setup macro-ish helpers ----
struct Setup {
    int c4, cA, cmask, imask;
    float pad0, pad1, pad2, pad3;
};

__device__ __forceinline__ Setup make_setup(int sIdx, int lane) {
    Setup s;
    const int cstart = sIdx * STR;
    s.c4 = cstart - 4 + lane * 4;
    s.cA = min(max(s.c4, 0), W - 4);
    s.cmask = 0; s.imask = 0;
#pragma unroll
    for (int k = 0; k < 4; ++k) {
        const int col = s.c4 + k;
        if (col >= cstart && col < cstart + STR && col < W) s.cmask |= 1 << k;
        if (col >= 0 && col < W)                            s.imask |= 1 << k;
    }
    s.pad0 = ((s.c4 + 0) < 3 || (s.c4 + 0) > W - 4) ? 0.f : NEG_INF;
    s.pad1 = ((s.c4 + 1) < 3 || (s.c4 + 1) > W - 4) ? 0.f : NEG_INF;
    s.pad2 = ((s.c4 + 2) < 3 || (s.c4 + 2) > W - 4) ? 0.f : NEG_INF;
    s.pad3 = ((s.c4 + 3) < 3 || (s.c4 + 3) > W - 4) ? 0.f : NEG_INF;
    return s;
}

// Load NR rows into registers with max MLP, then mask out-of-image cols/rows.
__device__ __forceinline__ void load_rows(const float* __restrict__ img,
                                          int r0, const Setup& s, F4 (&cur)[NR]) {
#pragma unroll
    for (int t = 0; t < NR; ++t) {
        const int irc = min(max(r0 - 3 + t, 0), H - 1);
        cur[t] = ld4(img + (size_t)irc * W + s.cA);
    }
#pragma unroll
    for (int t = 0; t < NR; ++t)
        asm volatile("" : "+v"(cur[t].x), "+v"(cur[t].y), "+v"(cur[t].z), "+v"(cur[t].w));
    if (s.imask != 0xF) {
#pragma unroll
        for (int t = 0; t < NR; ++t) {
            if (!(s.imask & 1)) cur[t].x = NEG_INF;
            if (!(s.imask & 2)) cur[t].y = NEG_INF;
            if (!(s.imask & 4)) cur[t].z = NEG_INF;
            if (!(s.imask & 8)) cur[t].w = NEG_INF;
        }
    }
#pragma unroll
    for (int t = 0; t < NR; ++t) {
        if (t < 3 || t >= NR - 3) {           // only prologue/epilogue rows can be OOB
            const int ir = r0 - 3 + t;
            if (ir < 0 || ir >= H) cur[t] = {NEG_INF, NEG_INF, NEG_INF, NEG_INF};
        }
    }
}

// Pass 1: per-image sums of dil_h and dil_v.
__global__ __launch_bounds__(256) void k_sums(const float* __restrict__ x,
                                              double* __restrict__ sums) {
    const int tid = threadIdx.x, lane = tid & 63, wid = tid >> 6;
    const int sIdx = blockIdx.x;             // stripe 0..8
    const int rr   = blockIdx.y * 4 + wid;   // row-chunk 0..255
    const int b    = blockIdx.z;
    const int r0   = rr * RC;
    const float* img = x + (size_t)b * H * W;
    const Setup s = make_setup(sIdx, lane);

    F4 cur[NR];
    load_rows(img, r0, s, cur);

    float shf = 0.f, svf = 0.f;
    // horizontal dilation rows r0..r1-1 (t in [3, 3+RC)), always in-image
#pragma unroll
    for (int t = 3; t < 3 + RC; ++t) {
        F4 c = cur[t];
        float la1 = __shfl_up(c.y, 1), la2 = __shfl_up(c.z, 1), la3 = __shfl_up(c.w, 1);
        float ra0 = __shfl_down(c.x, 1), ra1 = __shfl_down(c.y, 1), ra2 = __shfl_down(c.z, 1);
        float m0, m1, m2, m3;
        hmax7_4(la1, la2, la3, c.x, c.y, c.z, c.w, ra0, ra1, ra2, m0, m1, m2, m3);
        m0 = fmaxf(m0, s.pad0); m1 = fmaxf(m1, s.pad1);
        m2 = fmaxf(m2, s.pad2); m3 = fmaxf(m3, s.pad3);
        shf += ((s.cmask & 1) ? m0 : 0.f) + ((s.cmask & 2) ? m1 : 0.f)
             + ((s.cmask & 4) ? m2 : 0.f) + ((s.cmask & 8) ? m3 : 0.f);
    }
    // vertical dilation rows r0..r1-1 (window cur[jj..jj+6])
#pragma unroll
    for (int jj = 0; jj < RC; ++jj) {
        const int j = r0 + jj;
        const float rpad = (j < 3 || j > H - 4) ? 0.f : NEG_INF;
        float mx = fmax3(fmax3(cur[jj].x, cur[jj+1].x, cur[jj+2].x),
                         fmax3(cur[jj+3].x, cur[jj+4].x, cur[jj+5].x), cur[jj+6].x);
        float my = fmax3(fmax3(cur[jj].y, cur[jj+1].y, cur[jj+2].y),
                         fmax3(cur[jj+3].y, cur[jj+4].y, cur[jj+5].y), cur[jj+6].y);
        float mz = fmax3(fmax3(cur[jj].z, cur[jj+1].z, cur[jj+2].z),
                         fmax3(cur[jj+3].z, cur[jj+4].z, cur[jj+5].z), cur[jj+6].z);
        float mw = fmax3(fmax3(cur[jj].w, cur[jj+1].w, cur[jj+2].w),
                         fmax3(cur[jj+3].w, cur[jj+4].w, cur[jj+5].w), cur[jj+6].w);
        mx = fmaxf(mx, rpad); my = fmaxf(my, rpad);
        mz = fmaxf(mz, rpad); mw = fmaxf(mw, rpad);
        svf += ((s.cmask & 1) ? mx : 0.f) + ((s.cmask & 2) ? my : 0.f)
             + ((s.cmask & 4) ? mz : 0.f) + ((s.cmask & 8) ? mw : 0.f);
    }

    double sh = (double)shf, sv = (double)svf;
    for (int off = 32; off > 0; off >>= 1) {
        sh += __shfl_down(sh, off);
        sv += __shfl_down(sv, off);
    }
    if (lane == 0) {
        const int bk = rr & 63;
        atomicAdd(&sums[(b)      * 64 + bk], sh);
        atomicAdd(&sums[(8 + b)  * 64 + bk], sv);
    }
}

// Fold 64 buckets -> per-(orient,image) threshold.
__global__ void k_thr(const double* __restrict__ sums, float* __restrict__ thr) {
    const int p = threadIdx.x;   // 0..15
    if (p < 16) {
        const double* s = sums + p * 64;
        double a = 0.0;
        for (int i = 0; i < 64; ++i) a += s[i];
        thr[p] = (float)(a * (1.0 / ((double)H * (double)W)));
    }
}

// Pass 2 fused: both orientation counts from one register-resident row window.
__global__ __launch_bounds__(256) void k_counts(const float* __restrict__ x,
                                                const float* __restrict__ thr,
                                                unsigned int* __restrict__ cnts) {
    const int tid = threadIdx.x, lane = tid & 63, wid = tid >> 6;
    const int sIdx = blockIdx.x;
    const int rr   = blockIdx.y * 4 + wid;
    const int b    = blockIdx.z;
    const int r0   = rr * RC;
    const float* img = x + (size_t)b * H * W;
    const Setup s = make_setup(sIdx, lane);
    const float thr1 = thr[b], thr2 = thr[8 + b];

    F4 cur[NR];
    load_rows(img, r0, s, cur);

    // ---- orientation 1: bi over rows t in [1, NR-1); vertical 3-open as bit ops ----
    unsigned bc0 = 0, bc1 = 0, bc2 = 0, bc3 = 0;
#pragma unroll
    for (int t = 1; t < NR - 1; ++t) {
        F4 c = cur[t];
        float la1 = __shfl_up(c.y, 1), la2 = __shfl_up(c.z, 1), la3 = __shfl_up(c.w, 1);
        float ra0 = __shfl_down(c.x, 1), ra1 = __shfl_down(c.y, 1), ra2 = __shfl_down(c.z, 1);
        float m0, m1, m2, m3;
        hmax7_4(la1, la2, la3, c.x, c.y, c.z, c.w, ra0, ra1, ra2, m0, m1, m2, m3);
        m0 = fmaxf(m0, s.pad0); m1 = fmaxf(m1, s.pad1);
        m2 = fmaxf(m2, s.pad2); m3 = fmaxf(m3, s.pad3);
        bc0 |= (c.x > thr1 && c.x == m0) ? (1u << t) : 0u;
        bc1 |= (c.y > thr1 && c.y == m1) ? (1u << t) : 0u;
        bc2 |= (c.z > thr1 && c.z == m2) ? (1u << t) : 0u;
        bc3 |= (c.w > thr1 && c.w == m3) ? (1u << t) : 0u;
    }
    const unsigned rowm = ((1u << RC) - 1u) << 3;
    unsigned e0 = bc0 & (bc0 << 1) & (bc0 >> 1);
    unsigned e1 = bc1 & (bc1 << 1) & (bc1 >> 1);
    unsigned e2 = bc2 & (bc2 << 1) & (bc2 >> 1);
    unsigned e3 = bc3 & (bc3 << 1) & (bc3 >> 1);
    unsigned o0 = e0 | (e0 << 1) | (e0 >> 1);
    unsigned o1_ = e1 | (e1 << 1) | (e1 >> 1);
    unsigned o2_ = e2 | (e2 << 1) | (e2 >> 1);
    unsigned o3_ = e3 | (e3 << 1) | (e3 >> 1);
    unsigned cnt1 = ((s.cmask & 1) ? __popc(o0  & rowm) : 0u)
                  + ((s.cmask & 2) ? __popc(o1_ & rowm) : 0u)
                  + ((s.cmask & 4) ? __popc(o2_ & rowm) : 0u)
                  + ((s.cmask & 8) ? __popc(o3_ & rowm) : 0u);

    // ---- orientation 2: bi2 over rows jj in [0,RC); horizontal 3-open via bit-columns ----
    unsigned d0 = 0, d1 = 0, d2 = 0, d3 = 0;
#pragma unroll
    for (int jj = 0; jj < RC; ++jj) {
        const int j = r0 + jj;
        const float rpad = (j < 3 || j > H - 4) ? 0.f : NEG_INF;
        float mx = fmax3(fmax3(cur[jj].x, cur[jj+1].x, cur[jj+2].x),
                         fmax3(cur[jj+3].x, cur[jj+4].x, cur[jj+5].x), cur[jj+6].x);
        float my = fmax3(fmax3(cur[jj].y, cur[jj+1].y, cur[jj+2].y),
                         fmax3(cur[jj+3].y, cur[jj+4].y, cur[jj+5].y), cur[jj+6].y);
        float mz = fmax3(fmax3(cur[jj].z, cur[jj+1].z, cur[jj+2].z),
                         fmax3(cur[jj+3].z, cur[jj+4].z, cur[jj+5].z), cur[jj+6].z);
        float mw = fmax3(fmax3(cur[jj].w, cur[jj+1].w, cur[jj+2].w),
                         fmax3(cur[jj+3].w, cur[jj+4].w, cur[jj+5].w), cur[jj+6].w);
        mx = fmaxf(mx, rpad); my = fmaxf(my, rpad);
        mz = fmaxf(mz, rpad); mw = fmaxf(mw, rpad);
        F4 ce = cur[jj + 3];
        d0 |= (ce.x > thr2 && ce.x == mx) ? (1u << jj) : 0u;
        d1 |= (ce.y > thr2 && ce.y == my) ? (1u << jj) : 0u;
        d2 |= (ce.z > thr2 && ce.z == mz) ? (1u << jj) : 0u;
        d3 |= (ce.w > thr2 && ce.w == mw) ? (1u << jj) : 0u;
    }
    const unsigned pz = __shfl_up(d2, 1), pw = __shfl_up(d3, 1);
    const unsigned n0 = __shfl_down(d0, 1), n1 = __shfl_down(d1, 1);
    // erosion at cols c4-1 .. c4+4 (bitwise over rows); lanes 0/63 produce garbage
    // in pz/pw/n0/n1 but their outputs are cmask-discarded.
    const unsigned em1 = pz & pw & d0;
    const unsigned f0  = pw & d0 & d1;
    const unsigned f1  = d0 & d1 & d2;
    const unsigned f2  = d1 & d2 & d3;
    const unsigned f3  = d2 & d3 & n0;
    const unsigned fp4 = d3 & n0 & n1;
    const unsigned q0 = em1 | f0 | f1;
    const unsigned q1 = f0 | f1 | f2;
    const unsigned q2 = f1 | f2 | f3;
    const unsigned q3 = f2 | f3 | fp4;
    unsigned cnt2 = ((s.cmask & 1) ? __popc(q0) : 0u)
                  + ((s.cmask & 2) ? __popc(q1) : 0u)
                  + ((s.cmask & 4) ? __popc(q2) : 0u)
                  + ((s.cmask & 8) ? __popc(q3) : 0u);

    for (int off = 32; off > 0; off >>= 1) {
        cnt1 += __shfl_down(cnt1, off);
        cnt2 += __shfl_down(cnt2, off);
    }
    if (lane == 0) {
        const int bkt = (rr * 9 + sIdx) & 127;
        atomicAdd(&cnts[bkt],       cnt1);
        atomicAdd(&cnts[128 + bkt], cnt2);
    }
}

__global__ void k_final(const unsigned int* __restrict__ cnts,
                        int* __restrict__ out) {
    const int l = threadIdx.x;   // 64
    unsigned a = cnts[l] + cnts[64 + l];
    unsigned c = cnts[128 + l] + cnts[192 + l];
    for (int off = 32; off > 0; off >>= 1) {
        a += __shfl_down(a, off);
        c += __shfl_down(c, off);
    }
    if (l == 0) out[0] = (a < c) ? 1 : 0;
}

extern "C" void kernel_launch(void* const* d_in, const int* in_sizes, int n_in,
                              void* d_out, int out_size, void* d_ws, size_t ws_size,
                              hipStream_t stream) {
    const float* x = (const float*)d_in[0];
    int* out = (int*)d_out;
    double* sums = (double*)d_ws;                                 // [16][64] doubles
    float* thr = (float*)((char*)d_ws + 8192);                    // 16 floats
    unsigned int* cnts = (unsigned int*)((char*)d_ws + 8448);     // 256 uints

    hipMemsetAsync(d_ws, 0, 16384, stream);

    k_sums  <<<dim3(9, 64, 8), 256, 0, stream>>>(x, sums);
    k_thr   <<<1, 16, 0, stream>>>(sums, thr);
    k_counts<<<dim3(9, 64, 8), 256, 0, stream>>>(x, thr, cnts);
    k_final <<<1, 64, 0, stream>>>(cnts, out);
}